// Round 8
// baseline (150.137 us; speedup 1.0000x reference)
//
#include <hip/hip_runtime.h>
#include <hip/hip_bf16.h>
#include <math.h>

#define H_DIM 288
#define NHEADS 18
#define HEAD_D 16
#define SEQ 2048
#define BATCH 2
#define M_TOT (BATCH*SEQ)       // 4096
#define XCNT (M_TOT*H_DIM)      // 1179648

typedef _Float16 f16_t;
typedef __attribute__((ext_vector_type(4))) _Float16 half4v;
typedef __attribute__((ext_vector_type(8))) _Float16 half8v;
typedef __attribute__((ext_vector_type(4))) float   float4v;

__device__ __forceinline__ half8v f32x8_to_h8(float4 a, float4 b) {
    half8v h;
    h[0]=(f16_t)a.x; h[1]=(f16_t)a.y; h[2]=(f16_t)a.z; h[3]=(f16_t)a.w;
    h[4]=(f16_t)b.x; h[5]=(f16_t)b.y; h[6]=(f16_t)b.z; h[7]=(f16_t)b.w;
    return h;
}

// ---------------------------------------------------------------------------
// QKV projection via MFMA 16x16x32 f16, fp32 inputs converted in-register
// (no separate cvt pass, no LDS). One wave per block, tile M=32 x N=48.
// Grid (18, 128): z = bx/6 (0=Q,1=K,2=V), n0 = (bx%6)*48, m0 = by*32.
// Epilogue: Q,K -> RoPE -> f16 [b,h,s,d] (Q pre-scaled 0.25);
//           V -> f16 tiled Vt[bh][s>>4][d][s&15].
// ---------------------------------------------------------------------------
__global__ __launch_bounds__(64) void qkv_mfma(
    const float* __restrict__ X,
    const float* __restrict__ Wq, const float* __restrict__ Wk, const float* __restrict__ Wv,
    f16_t* __restrict__ Q16, f16_t* __restrict__ K16, f16_t* __restrict__ Vt)
{
    const int bx = blockIdx.x;          // 0..17
    const int z  = bx/6;
    const int n0 = (bx - z*6)*48;
    const int m0 = blockIdx.y*32;
    const int lane = threadIdx.x & 63;
    const int n = lane & 15, quad = lane >> 4;

    const float* W = (z == 0) ? Wq : (z == 1) ? Wk : Wv;

    float4v acc[2][3];
    #pragma unroll
    for (int mt = 0; mt < 2; mt++)
        #pragma unroll
        for (int nt = 0; nt < 3; nt++)
            acc[mt][nt] = (float4v){0.f,0.f,0.f,0.f};

    for (int k0 = 0; k0 < H_DIM; k0 += 32) {
        half8v a[2], b[3];
        #pragma unroll
        for (int mt = 0; mt < 2; mt++) {
            const float4* p = (const float4*)(X + (size_t)(m0 + mt*16 + n)*H_DIM + k0 + quad*8);
            a[mt] = f32x8_to_h8(p[0], p[1]);
        }
        #pragma unroll
        for (int nt = 0; nt < 3; nt++) {
            const float4* p = (const float4*)(W + (size_t)(n0 + nt*16 + n)*H_DIM + k0 + quad*8);
            b[nt] = f32x8_to_h8(p[0], p[1]);
        }
        #pragma unroll
        for (int mt = 0; mt < 2; mt++)
            #pragma unroll
            for (int nt = 0; nt < 3; nt++)
                acc[mt][nt] = __builtin_amdgcn_mfma_f32_16x16x32_f16(a[mt], b[nt], acc[mt][nt], 0, 0, 0);
    }

    if (z < 2) {   // Q or K: RoPE epilogue
        f16_t* dst = (z == 0) ? Q16 : K16;
        const float invf = exp2f(-1.6609640474436813f * (float)(n & 7));
        #pragma unroll
        for (int mt = 0; mt < 2; mt++) {
            #pragma unroll
            for (int r = 0; r < 4; r++) {
                int m = m0 + mt*16 + quad*4 + r;
                int bb = m >> 11, s = m & (SEQ - 1);
                float ang = (float)s * invf;
                float c, sn;
                sincosf(ang, &sn, &c);
                #pragma unroll
                for (int nt = 0; nt < 3; nt++) {
                    float own = acc[mt][nt][r];
                    float par = __shfl_xor(own, 8, 64);
                    float val = (n & 8) ? fmaf(own, c, par*sn) : fmaf(own, c, -par*sn);
                    if (z == 0) val *= 0.25f;        // fold 1/sqrt(HEAD_D)
                    int head = (n0 >> 4) + nt;
                    dst[((size_t)((bb*NHEADS + head)*SEQ) + s)*HEAD_D + n] = (f16_t)val;
                }
            }
        }
    } else {       // V: transposed tiled store
        #pragma unroll
        for (int mt = 0; mt < 2; mt++)
            #pragma unroll
            for (int nt = 0; nt < 3; nt++)
                #pragma unroll
                for (int r = 0; r < 4; r++) {
                    int m = m0 + mt*16 + quad*4 + r;
                    int bb = m >> 11, s = m & (SEQ - 1);
                    int head = (n0 >> 4) + nt;
                    Vt[(size_t)(bb*NHEADS + head)*(SEQ*HEAD_D)
                       + (size_t)(s >> 4)*256 + n*16 + (s & 15)] = (f16_t)acc[mt][nt][r];
                }
    }
}

// ---------------------------------------------------------------------------
// MFMA flash attention v3: block = 4 waves, 64 queries (four 16-q tiles
// sharing every K/V load), key tiles strided across waves (kt = wave+4i),
// register prefetch, lane-contiguous LDS reduction, LPT order.
//   S^T = MFMA(A=K_tile, B=Q^T); P = exp(S^T) (fixed max 0);
//   C-layout of S^T == B-frag layout => P feeds PV directly:
//   O^T += MFMA(A=V^T_tile, B=P^T).
// Tile-activity checks are wave-uniform (kt, qp scalar) -> scalar branches.
// ---------------------------------------------------------------------------
__global__ __launch_bounds__(256) void attn_mfma(
    const f16_t* __restrict__ Q16, const f16_t* __restrict__ K16,
    const f16_t* __restrict__ Vt, f16_t* __restrict__ Of)
{
    const int qp   = 31 - blockIdx.x;     // LPT: heaviest blocks first
    const int bh   = blockIdx.y;          // 0..35
    const int wave = threadIdx.x >> 6;
    const int lane = threadIdx.x & 63;
    const int n    = lane & 15;
    const int quad = lane >> 4;
    const int b = bh / NHEADS, h = bh - b*NHEADS;
    const int q0 = qp * 64;

    __shared__ float sacc[4][4][4][64];   // [wave][tile][reg][lane] - conflict-free
    __shared__ float sl[4][4][64];

    half4v qb[4];
    #pragma unroll
    for (int t = 0; t < 4; t++)
        qb[t] = *(const half4v*)(Q16 + ((size_t)bh*SEQ + q0 + t*16 + n)*HEAD_D + quad*4);
    const f16_t* Kb = K16 + (size_t)bh * SEQ * HEAD_D;
    const f16_t* Vb = Vt  + (size_t)bh * SEQ * HEAD_D;

    const float4v zero = {0.f, 0.f, 0.f, 0.f};
    float4v acc[4] = {zero, zero, zero, zero};
    float l[4] = {0.f, 0.f, 0.f, 0.f};

    const int ktmax = 4*qp + 3;           // diag of tile t sits at kt == 4*qp+t
    int kt = wave;
    half4v ka, va;
    if (kt <= ktmax) {
        ka = *(const half4v*)(Kb + (size_t)(kt*16 + n)*HEAD_D + quad*4);
        va = *(const half4v*)(Vb + (size_t)kt*256 + n*16 + quad*4);
    }
    for (; kt <= ktmax; kt += 4) {
        half4v kan, van;
        if (kt + 4 <= ktmax) {
            kan = *(const half4v*)(Kb + (size_t)((kt+4)*16 + n)*HEAD_D + quad*4);
            van = *(const half4v*)(Vb + (size_t)(kt+4)*256 + n*16 + quad*4);
        }
        #pragma unroll
        for (int t = 0; t < 4; t++) {
            const int lim = 4*qp + t;     // wave-uniform
            if (kt > lim) continue;       // inactive tile: scalar skip
            float4v s = __builtin_amdgcn_mfma_f32_16x16x16f16(ka, qb[t], zero, 0, 0, 0);
            float p[4];
            if (kt == lim) {              // diagonal: causal mask
                #pragma unroll
                for (int r = 0; r < 4; r++) {
                    float e = __expf(s[r]);
                    p[r] = (quad*4 + r <= n) ? e : 0.0f;
                }
            } else {
                #pragma unroll
                for (int r = 0; r < 4; r++) p[r] = __expf(s[r]);
            }
            l[t] += (p[0] + p[1]) + (p[2] + p[3]);
            half4v pb;
            pb[0]=(f16_t)p[0]; pb[1]=(f16_t)p[1]; pb[2]=(f16_t)p[2]; pb[3]=(f16_t)p[3];
            acc[t] = __builtin_amdgcn_mfma_f32_16x16x16f16(va, pb, acc[t], 0, 0, 0);
        }
        ka = kan; va = van;
    }

    #pragma unroll
    for (int t = 0; t < 4; t++) {
        #pragma unroll
        for (int r = 0; r < 4; r++) sacc[wave][t][r][lane] = acc[t][r];
        sl[wave][t][lane] = l[t];
    }
    __syncthreads();

    {   // wave t reduces tile t
        const int t = wave;
        float a[4] = {0.f, 0.f, 0.f, 0.f};
        float lsum = 0.f;
        #pragma unroll
        for (int w = 0; w < 4; w++) {
            lsum += sl[w][t][lane];
            #pragma unroll
            for (int r = 0; r < 4; r++) a[r] += sacc[w][t][r][lane];
        }
        lsum += __shfl_xor(lsum, 16, 64);
        lsum += __shfl_xor(lsum, 32, 64);
        float inv = 1.0f / lsum;
        half4v o;
        o[0]=(f16_t)(a[0]*inv); o[1]=(f16_t)(a[1]*inv);
        o[2]=(f16_t)(a[2]*inv); o[3]=(f16_t)(a[3]*inv);
        *(half4v*)(Of + (size_t)(b*SEQ + q0 + t*16 + n)*H_DIM + h*HEAD_D + quad*4) = o;
    }
}

// ---------------------------------------------------------------------------
// Output projection via MFMA, no LDS. Wo fp32 converted in-register.
// Tile M=32 x N=48, grid (6, 128). fp32 store to d_out.
// ---------------------------------------------------------------------------
__global__ __launch_bounds__(64) void out_mfma(
    const f16_t* __restrict__ Of, const float* __restrict__ Wo,
    float* __restrict__ C)
{
    const int n0 = blockIdx.x * 48;
    const int m0 = blockIdx.y * 32;
    const int lane = threadIdx.x & 63;
    const int n = lane & 15, quad = lane >> 4;

    float4v acc[2][3];
    #pragma unroll
    for (int mt = 0; mt < 2; mt++)
        #pragma unroll
        for (int nt = 0; nt < 3; nt++)
            acc[mt][nt] = (float4v){0.f,0.f,0.f,0.f};

    for (int k0 = 0; k0 < H_DIM; k0 += 32) {
        half8v a[2], b[3];
        #pragma unroll
        for (int mt = 0; mt < 2; mt++)
            a[mt] = *(const half8v*)(Of + (size_t)(m0 + mt*16 + n)*H_DIM + k0 + quad*8);
        #pragma unroll
        for (int nt = 0; nt < 3; nt++) {
            const float4* p = (const float4*)(Wo + (size_t)(n0 + nt*16 + n)*H_DIM + k0 + quad*8);
            b[nt] = f32x8_to_h8(p[0], p[1]);
        }
        #pragma unroll
        for (int mt = 0; mt < 2; mt++)
            #pragma unroll
            for (int nt = 0; nt < 3; nt++)
                acc[mt][nt] = __builtin_amdgcn_mfma_f32_16x16x32_f16(a[mt], b[nt], acc[mt][nt], 0, 0, 0);
    }
    #pragma unroll
    for (int mt = 0; mt < 2; mt++)
        #pragma unroll
        for (int nt = 0; nt < 3; nt++)
            #pragma unroll
            for (int r = 0; r < 4; r++) {
                int m = m0 + mt*16 + quad*4 + r;
                C[(size_t)m*H_DIM + n0 + nt*16 + n] = acc[mt][nt][r];
            }
}

// ---------------------------------------------------------------------------
extern "C" void kernel_launch(void* const* d_in, const int* in_sizes, int n_in,
                              void* d_out, int out_size, void* d_ws, size_t ws_size,
                              hipStream_t stream)
{
    const float* Xh = (const float*)d_in[0];
    const float* Wq = (const float*)d_in[1];
    const float* Wk = (const float*)d_in[2];
    const float* Wv = (const float*)d_in[3];
    const float* Wo = (const float*)d_in[4];
    float* out = (float*)d_out;

    f16_t* Q16 = (f16_t*)d_ws;          // XCNT
    f16_t* K16 = Q16 + XCNT;            // XCNT
    f16_t* Vt  = K16 + XCNT;            // XCNT
    f16_t* Of  = Vt + XCNT;             // XCNT  (total ~9.4 MB)

    qkv_mfma<<<dim3(18, 128), 64, 0, stream>>>(Xh, Wq, Wk, Wv, Q16, K16, Vt);
    attn_mfma<<<dim3(32, 36), 256, 0, stream>>>(Q16, K16, Vt, Of);
    out_mfma<<<dim3(6, 128), 64, 0, stream>>>(Of, Wo, out);
}

// Round 9
// 116.584 us; speedup vs baseline: 1.2878x; 1.2878x over previous
//
#include <hip/hip_runtime.h>
#include <hip/hip_bf16.h>
#include <math.h>

#define H_DIM 288
#define NHEADS 18
#define HEAD_D 16
#define SEQ 2048
#define BATCH 2
#define M_TOT (BATCH*SEQ)       // 4096
#define XCNT (M_TOT*H_DIM)      // 1179648
#define WCNT (H_DIM*H_DIM)      // 82944
#define NUNITS 10368            // 36 bh x 288 (qp,chunk) units
#define NQUNITS 2304            // 36 bh x 64 qp

typedef _Float16 f16_t;
typedef __attribute__((ext_vector_type(4))) _Float16 half4v;
typedef __attribute__((ext_vector_type(8))) _Float16 half8v;
typedef __attribute__((ext_vector_type(4))) float   float4v;

// ---------------------------------------------------------------------------
// fp32 -> f16 convert: X (4096x288) and the four 288x288 weights.
// ---------------------------------------------------------------------------
__global__ __launch_bounds__(256) void cvt_f16(
    const float* __restrict__ X,
    const float* __restrict__ Wq, const float* __restrict__ Wk,
    const float* __restrict__ Wv, const float* __restrict__ Wo,
    f16_t* __restrict__ Xf, f16_t* __restrict__ Wf)
{
    int idx = blockIdx.x * 256 + threadIdx.x;
    const int X4 = XCNT/4, W4 = WCNT/4;
    if (idx >= X4 + 4*W4) return;
    const float* src; f16_t* dst; int off;
    if (idx < X4) { src = X; dst = Xf; off = idx; }
    else {
        int r = idx - X4;
        int wz = r / W4; off = r - wz*W4;
        src = (wz==0) ? Wq : (wz==1) ? Wk : (wz==2) ? Wv : Wo;
        dst = Wf + (size_t)wz*WCNT;
    }
    float4 v = ((const float4*)src)[off];
    half4v h; h[0]=(f16_t)v.x; h[1]=(f16_t)v.y; h[2]=(f16_t)v.z; h[3]=(f16_t)v.w;
    ((half4v*)dst)[off] = h;
}

// ---------------------------------------------------------------------------
// QKV projection via MFMA 16x16x32 f16 (R7-proven). One wave per block,
// tile M=32 x N=48. Grid (18,128): z=bx/6, n0=(bx%6)*48, m0=by*32.
// Epilogue: Q,K -> RoPE -> f16 [b,h,s,d]; Q pre-scaled 0.25*log2(e) so the
// attention softmax can use raw exp2. V -> f16 tiled Vt[bh][s>>4][d][s&15].
// ---------------------------------------------------------------------------
__global__ __launch_bounds__(64) void qkv_mfma(
    const f16_t* __restrict__ Xf, const f16_t* __restrict__ Wf,
    f16_t* __restrict__ Q16, f16_t* __restrict__ K16, f16_t* __restrict__ Vt)
{
    const int bx = blockIdx.x;          // 0..17
    const int z  = bx/6;
    const int n0 = (bx - z*6)*48;
    const int m0 = blockIdx.y*32;
    const int lane = threadIdx.x & 63;
    const int n = lane & 15, quad = lane >> 4;

    const f16_t* W = Wf + (size_t)z*WCNT;

    float4v acc[2][3];
    #pragma unroll
    for (int mt = 0; mt < 2; mt++)
        #pragma unroll
        for (int nt = 0; nt < 3; nt++)
            acc[mt][nt] = (float4v){0.f,0.f,0.f,0.f};

    for (int k0 = 0; k0 < H_DIM; k0 += 32) {
        half8v a[2], b[3];
        #pragma unroll
        for (int mt = 0; mt < 2; mt++)
            a[mt] = *(const half8v*)(Xf + (size_t)(m0 + mt*16 + n)*H_DIM + k0 + quad*8);
        #pragma unroll
        for (int nt = 0; nt < 3; nt++)
            b[nt] = *(const half8v*)(W + (size_t)(n0 + nt*16 + n)*H_DIM + k0 + quad*8);
        #pragma unroll
        for (int mt = 0; mt < 2; mt++)
            #pragma unroll
            for (int nt = 0; nt < 3; nt++)
                acc[mt][nt] = __builtin_amdgcn_mfma_f32_16x16x32_f16(a[mt], b[nt], acc[mt][nt], 0, 0, 0);
    }

    if (z < 2) {   // Q or K: RoPE epilogue
        f16_t* dst = (z == 0) ? Q16 : K16;
        const float invf = exp2f(-1.6609640474436813f * (float)(n & 7));
        #pragma unroll
        for (int mt = 0; mt < 2; mt++) {
            #pragma unroll
            for (int r = 0; r < 4; r++) {
                int m = m0 + mt*16 + quad*4 + r;
                int bb = m >> 11, s = m & (SEQ - 1);
                float ang = (float)s * invf;
                float c, sn;
                sincosf(ang, &sn, &c);
                #pragma unroll
                for (int nt = 0; nt < 3; nt++) {
                    float own = acc[mt][nt][r];
                    float par = __shfl_xor(own, 8, 64);
                    float val = (n & 8) ? fmaf(own, c, par*sn) : fmaf(own, c, -par*sn);
                    if (z == 0) val *= 0.36067376022224085f;  // 0.25 * log2(e)
                    int head = (n0 >> 4) + nt;
                    dst[((size_t)((bb*NHEADS + head)*SEQ) + s)*HEAD_D + n] = (f16_t)val;
                }
            }
        }
    } else {       // V: transposed tiled store
        #pragma unroll
        for (int mt = 0; mt < 2; mt++)
            #pragma unroll
            for (int nt = 0; nt < 3; nt++)
                #pragma unroll
                for (int r = 0; r < 4; r++) {
                    int m = m0 + mt*16 + quad*4 + r;
                    int bb = m >> 11, s = m & (SEQ - 1);
                    int head = (n0 >> 4) + nt;
                    Vt[(size_t)(bb*NHEADS + head)*(SEQ*HEAD_D)
                       + (size_t)(s >> 4)*256 + n*16 + (s & 15)] = (f16_t)acc[mt][nt][r];
                }
    }
}

// ---------------------------------------------------------------------------
// Flash attention phase 1: work-uniform split-K. One wave per unit
// (bh, qp, chunk): 32 queries (2 q-tiles), up to 16 key tiles. Partial
// (acc per tile, l per lane) written to ws. No LDS, ~30 VGPRs.
// Unit count per bh: qp in 8 groups g=qp>>3, nch=g+1 -> 288 units.
//   S^T = MFMA(A=K, B=Q^T); P = exp2(S^T) (Q pre-scaled by log2e/4);
//   C-layout == B-frag layout => P feeds O^T += MFMA(A=V^T, B=P^T).
// ---------------------------------------------------------------------------
__global__ __launch_bounds__(256) void attn_part(
    const f16_t* __restrict__ Q16, const f16_t* __restrict__ K16,
    const f16_t* __restrict__ Vt,
    float4* __restrict__ accbuf, float* __restrict__ lbuf)
{
    const int unit = blockIdx.x*4 + (threadIdx.x >> 6);   // 0..10367
    const int lane = threadIdx.x & 63;
    const int n = lane & 15, quad = lane >> 4;

    const int bh = unit / 288;
    const int rem = unit - bh*288;
    int g, t0;
    if      (rem < 8)   { g=0; t0=rem;     }
    else if (rem < 24)  { g=1; t0=rem-8;   }
    else if (rem < 48)  { g=2; t0=rem-24;  }
    else if (rem < 80)  { g=3; t0=rem-48;  }
    else if (rem < 120) { g=4; t0=rem-80;  }
    else if (rem < 168) { g=5; t0=rem-120; }
    else if (rem < 224) { g=6; t0=rem-168; }
    else                { g=7; t0=rem-224; }
    const int qd = t0 / (g+1);
    const int qp = 8*g + qd;            // 0..63: query pair index (32 queries)
    const int chunk = t0 - qd*(g+1);
    const int q0 = qp*32;

    half4v qb0 = *(const half4v*)(Q16 + ((size_t)bh*SEQ + q0 + n)*HEAD_D + quad*4);
    half4v qb1 = *(const half4v*)(Q16 + ((size_t)bh*SEQ + q0 + 16 + n)*HEAD_D + quad*4);
    const f16_t* Kb = K16 + (size_t)bh * SEQ * HEAD_D;
    const f16_t* Vb = Vt  + (size_t)bh * SEQ * HEAD_D;

    const float4v zero = {0.f, 0.f, 0.f, 0.f};
    float4v acc0 = zero, acc1 = zero;
    float l0 = 0.f, l1 = 0.f;

    const int lim0 = 2*qp, lim1 = 2*qp + 1;   // diagonal kts for tiles 0,1
    const int ktlo = chunk*16;
    const int kthi = min(ktlo + 15, lim1);

    int kt = ktlo;
    half4v ka = *(const half4v*)(Kb + (size_t)(kt*16 + n)*HEAD_D + quad*4);
    half4v va = *(const half4v*)(Vb + (size_t)kt*256 + n*16 + quad*4);
    for (; kt <= kthi; kt++) {
        half4v kan, van;
        if (kt < kthi) {
            kan = *(const half4v*)(Kb + (size_t)((kt+1)*16 + n)*HEAD_D + quad*4);
            van = *(const half4v*)(Vb + (size_t)(kt+1)*256 + n*16 + quad*4);
        }
        {   // tile 1 (queries q0+16..31): active for all kt <= lim1
            float4v s = __builtin_amdgcn_mfma_f32_16x16x16f16(ka, qb1, zero, 0, 0, 0);
            float p[4];
            #pragma unroll
            for (int r = 0; r < 4; r++) {
                float e = __builtin_amdgcn_exp2f(s[r]);
                p[r] = (kt == lim1 && quad*4 + r > n) ? 0.0f : e;
            }
            l1 += (p[0] + p[1]) + (p[2] + p[3]);
            half4v pb;
            pb[0]=(f16_t)p[0]; pb[1]=(f16_t)p[1]; pb[2]=(f16_t)p[2]; pb[3]=(f16_t)p[3];
            acc1 = __builtin_amdgcn_mfma_f32_16x16x16f16(va, pb, acc1, 0, 0, 0);
        }
        if (kt <= lim0) {   // tile 0 (queries q0..15)
            float4v s = __builtin_amdgcn_mfma_f32_16x16x16f16(ka, qb0, zero, 0, 0, 0);
            float p[4];
            #pragma unroll
            for (int r = 0; r < 4; r++) {
                float e = __builtin_amdgcn_exp2f(s[r]);
                p[r] = (kt == lim0 && quad*4 + r > n) ? 0.0f : e;
            }
            l0 += (p[0] + p[1]) + (p[2] + p[3]);
            half4v pb;
            pb[0]=(f16_t)p[0]; pb[1]=(f16_t)p[1]; pb[2]=(f16_t)p[2]; pb[3]=(f16_t)p[3];
            acc0 = __builtin_amdgcn_mfma_f32_16x16x16f16(va, pb, acc0, 0, 0, 0);
        }
        ka = kan; va = van;
    }

    float4 a0; a0.x=acc0[0]; a0.y=acc0[1]; a0.z=acc0[2]; a0.w=acc0[3];
    float4 a1; a1.x=acc1[0]; a1.y=acc1[1]; a1.z=acc1[2]; a1.w=acc1[3];
    accbuf[((size_t)unit*2 + 0)*64 + lane] = a0;
    accbuf[((size_t)unit*2 + 1)*64 + lane] = a1;
    lbuf[((size_t)unit*2 + 0)*64 + lane] = l0;
    lbuf[((size_t)unit*2 + 1)*64 + lane] = l1;
}

// ---------------------------------------------------------------------------
// Flash attention phase 2: one wave per (bh, qp) sums <=8 chunk partials,
// normalizes, writes f16 O. Unit prefix: U(qp)=qp+4g(g-1)+g*j, g=qp>>3, j=qp&7.
// ---------------------------------------------------------------------------
__global__ __launch_bounds__(256) void attn_red(
    const float4* __restrict__ accbuf, const float* __restrict__ lbuf,
    f16_t* __restrict__ Of)
{
    const int wid = blockIdx.x*4 + (threadIdx.x >> 6);    // 0..2303
    const int lane = threadIdx.x & 63;
    const int n = lane & 15, quad = lane >> 4;
    const int bh = wid >> 6, qp = wid & 63;
    const int b = bh / NHEADS, h = bh - b*NHEADS;
    const int g = qp >> 3, j = qp & 7;
    const int nch = g + 1;
    const int ubase = bh*288 + qp + 4*g*(g-1) + g*j;

    #pragma unroll
    for (int t = 0; t < 2; t++) {
        float4 a = {0.f, 0.f, 0.f, 0.f};
        float l = 0.f;
        for (int c = 0; c < nch; c++) {
            size_t idx = ((size_t)(ubase + c)*2 + t)*64 + lane;
            float4 v = accbuf[idx];
            a.x += v.x; a.y += v.y; a.z += v.z; a.w += v.w;
            l += lbuf[idx];
        }
        l += __shfl_xor(l, 16, 64);
        l += __shfl_xor(l, 32, 64);
        float inv = 1.0f / l;
        half4v o;
        o[0]=(f16_t)(a.x*inv); o[1]=(f16_t)(a.y*inv);
        o[2]=(f16_t)(a.z*inv); o[3]=(f16_t)(a.w*inv);
        *(half4v*)(Of + (size_t)(b*SEQ + qp*32 + t*16 + n)*H_DIM + h*HEAD_D + quad*4) = o;
    }
}

// ---------------------------------------------------------------------------
// Output projection via MFMA (R7-proven). Tile M=32 x N=48, grid (6,128).
// ---------------------------------------------------------------------------
__global__ __launch_bounds__(64) void out_mfma(
    const f16_t* __restrict__ Of, const f16_t* __restrict__ Wo16,
    float* __restrict__ C)
{
    const int n0 = blockIdx.x * 48;
    const int m0 = blockIdx.y * 32;
    const int lane = threadIdx.x & 63;
    const int n = lane & 15, quad = lane >> 4;

    float4v acc[2][3];
    #pragma unroll
    for (int mt = 0; mt < 2; mt++)
        #pragma unroll
        for (int nt = 0; nt < 3; nt++)
            acc[mt][nt] = (float4v){0.f,0.f,0.f,0.f};

    for (int k0 = 0; k0 < H_DIM; k0 += 32) {
        half8v a[2], b[3];
        #pragma unroll
        for (int mt = 0; mt < 2; mt++)
            a[mt] = *(const half8v*)(Of + (size_t)(m0 + mt*16 + n)*H_DIM + k0 + quad*8);
        #pragma unroll
        for (int nt = 0; nt < 3; nt++)
            b[nt] = *(const half8v*)(Wo16 + (size_t)(n0 + nt*16 + n)*H_DIM + k0 + quad*8);
        #pragma unroll
        for (int mt = 0; mt < 2; mt++)
            #pragma unroll
            for (int nt = 0; nt < 3; nt++)
                acc[mt][nt] = __builtin_amdgcn_mfma_f32_16x16x32_f16(a[mt], b[nt], acc[mt][nt], 0, 0, 0);
    }
    #pragma unroll
    for (int mt = 0; mt < 2; mt++)
        #pragma unroll
        for (int nt = 0; nt < 3; nt++)
            #pragma unroll
            for (int r = 0; r < 4; r++) {
                int m = m0 + mt*16 + quad*4 + r;
                C[(size_t)m*H_DIM + n0 + nt*16 + n] = acc[mt][nt][r];
            }
}

// ---------------------------------------------------------------------------
extern "C" void kernel_launch(void* const* d_in, const int* in_sizes, int n_in,
                              void* d_out, int out_size, void* d_ws, size_t ws_size,
                              hipStream_t stream)
{
    const float* Xh = (const float*)d_in[0];
    const float* Wq = (const float*)d_in[1];
    const float* Wk = (const float*)d_in[2];
    const float* Wv = (const float*)d_in[3];
    const float* Wo = (const float*)d_in[4];
    float* out = (float*)d_out;

    f16_t* Xf  = (f16_t*)d_ws;                  // XCNT
    f16_t* Wf  = Xf + XCNT;                     // 4*WCNT
    f16_t* Q16 = Wf + 4*(size_t)WCNT;           // XCNT
    f16_t* K16 = Q16 + XCNT;                    // XCNT
    f16_t* Vt  = K16 + XCNT;                    // XCNT
    f16_t* Of  = Vt + XCNT;                     // XCNT
    float4* accbuf = (float4*)(Of + XCNT);      // NUNITS*2*64 float4 = 21.2 MB
    float*  lbuf   = (float*)(accbuf + (size_t)NUNITS*2*64);  // 5.3 MB

    const int total4 = (XCNT + 4*WCNT)/4;
    cvt_f16<<<dim3((total4 + 255)/256), 256, 0, stream>>>(Xh, Wq, Wk, Wv, Wo, Xf, Wf);
    qkv_mfma<<<dim3(18, 128), 64, 0, stream>>>(Xf, Wf, Q16, K16, Vt);
    attn_part<<<dim3(NUNITS/4), 256, 0, stream>>>(Q16, K16, Vt, accbuf, lbuf);
    attn_red<<<dim3(NQUNITS/4), 256, 0, stream>>>(accbuf, lbuf, Of);
    out_mfma<<<dim3(6, 128), 64, 0, stream>>>(Of, Wf + 3*(size_t)WCNT, out);
}